// Round 9
// baseline (117.279 us; speedup 1.0000x reference)
//
#include <hip/hip_runtime.h>

#define N 8192
#define D 256

typedef short short8 __attribute__((ext_vector_type(8)));
typedef float f32x4 __attribute__((ext_vector_type(4)));

__device__ __forceinline__ unsigned short f2bf(float f) {
    unsigned int u = __float_as_uint(f);
    u += 0x7fffu + ((u >> 16) & 1u);   // RNE
    return (unsigned short)(u >> 16);
}
__device__ __forceinline__ float bf2f(unsigned short h) {
    return __uint_as_float(((unsigned int)h) << 16);
}

// async global->LDS, 16B per lane; dst is wave-uniform base, lane i lands at dst + i*16
#define GLDS16(g, l) __builtin_amdgcn_global_load_lds(                      \
    (const __attribute__((address_space(1))) void*)(g),                     \
    (__attribute__((address_space(3))) void*)(l), 16, 0, 0)

// Kernel 0: fp32 -> bf16 pre-conversion + row squared norms (of bf16-rounded
// values, consistent with the MFMA Gram) + zero the S/L accumulators.
__global__ __launch_bounds__(256) void k_cvt(const float* __restrict__ x,
                                             unsigned short* __restrict__ xb,
                                             float* __restrict__ sq,
                                             float* __restrict__ Sarr,
                                             float* __restrict__ Larr) {
    const int wv = threadIdx.x >> 6, lane = threadIdx.x & 63;
    const int row = blockIdx.x * 4 + wv;
    const float4 v = ((const float4*)x)[(size_t)row * 64 + lane];
    unsigned short pa = f2bf(v.x), pb = f2bf(v.y), pc = f2bf(v.z), pd = f2bf(v.w);
    float a = bf2f(pa), b = bf2f(pb), c = bf2f(pc), d = bf2f(pd);
    float s = a * a + b * b + c * c + d * d;
    ((ushort4*)xb)[(size_t)row * 64 + lane] = make_ushort4(pa, pb, pc, pd);
#pragma unroll
    for (int m = 1; m < 64; m <<= 1) s += __shfl_xor(s, m, 64);
    if (lane == 0) {
        sq[row] = s;
        Sarr[row] = 0.0f;
        Larr[row] = 0.0f;
    }
}

// Kernel 1: R8 config (64 rows/wave, 256-row blocks, screened exp2 epilogue)
// with two latency fixes:
//  (a) 64-col LDS tiles (2 x 32 KB ping-pong) -> 8 barriers/block vs 16;
//  (b) per 16-col sub-tile, bv loads batched 4+4 into registers so LDS
//      latency is paid once per 16-MFMA stretch, not per kk.
// Grid (32,16) = 512 blocks = 2/CU (LDS 64 KB -> exactly 2 resident).
__global__ __launch_bounds__(256, 2) void k_gram(const unsigned short* __restrict__ xb,
                                                 const float* __restrict__ sq,
                                                 const float* __restrict__ temp,
                                                 float* __restrict__ Sarr,
                                                 float* __restrict__ Larr) {
    __shared__ unsigned short Bs[2][64 * D];   // 2 x 32 KB, 16B-chunk XOR swizzled

    const int tid = threadIdx.x;
    const int wv = tid >> 6, lane = tid & 63;
    const int q8 = lane >> 4, c = lane & 15;
    const int rowbase = blockIdx.x * 256;
    const int ybase = blockIdx.y * 512;
    const float T = temp[0];
    const float LOG2E = 1.44269504f;
    const float s2 = -LOG2E / (2.0f * T * T);   // log2-scaled; t2 = c2*g + ar + bc
    const float c2 = -2.0f * s2;

    // A fragments in registers: wave wv owns rows rowbase + wv*64 .. +63
    short8 av[4][8];
#pragma unroll
    for (int tr = 0; tr < 4; ++tr) {
        const unsigned short* ap = xb + (size_t)(rowbase + wv * 64 + tr * 16 + c) * D;
#pragma unroll
        for (int kk = 0; kk < 8; ++kk)
            av[tr][kk] = *(const short8*)(ap + kk * 32 + q8 * 8);
    }
    float ar[16];   // sq[row] * s2 (negative)
#pragma unroll
    for (int tr = 0; tr < 4; ++tr)
#pragma unroll
        for (int r = 0; r < 4; ++r)
            ar[tr * 4 + r] = sq[rowbase + wv * 64 + tr * 16 + q8 * 4 + r] * s2;
    float armax = ar[0];
#pragma unroll
    for (int k = 1; k < 16; ++k) armax = fmaxf(armax, ar[k]);

    // LDS read swizzle precompute (B-rows this lane touches: tc*16 + c)
    const int rx = c & 7;

    // staging decomposition: 32 KB/tile = 32 segs of 1 KB (2 B-cols);
    // wave wv stages segs wv*8 .. wv*8+7
    const int seg0 = wv * 8;
    const int rhalf = lane >> 5, slot = lane & 31;

    float Sr[16], Mr[16];
#pragma unroll
    for (int k = 0; k < 16; ++k) { Sr[k] = 0.f; Mr[k] = 0.f; }

    // prologue: stage tile 0 into buffer 0
#pragma unroll
    for (int g2 = 0; g2 < 8; ++g2) {
        int seg = seg0 + g2;
        int row = seg * 2 + rhalf;
        int g = slot ^ (row & 7);
        GLDS16(xb + (size_t)(ybase + row) * D + g * 8, &Bs[0][0] + seg * 512);
    }

    for (int ht = 0; ht < 8; ++ht) {
        const int tilebase = ybase + ht * 64;
        const int cur = ht & 1;

        __syncthreads();   // drains stage of ht; fences buffer reuse (ht-2)

        if (ht < 7) {
            const int nb = tilebase + 64;
#pragma unroll
            for (int g2 = 0; g2 < 8; ++g2) {
                int seg = seg0 + g2;
                int row = seg * 2 + rhalf;
                int g = slot ^ (row & 7);
                GLDS16(xb + (size_t)(nb + row) * D + g * 8, &Bs[cur ^ 1][0] + seg * 512);
            }
        }

#pragma unroll
        for (int tc = 0; tc < 4; ++tc) {
            const float bc = sq[tilebase + tc * 16 + c] * s2;
            const unsigned short* bbase = &Bs[cur][0] + (tc * 16 + c) * D;

            // batch-load first half of B fragments (kk = 0..3)
            short8 bva[4];
#pragma unroll
            for (int kk = 0; kk < 4; ++kk)
                bva[kk] = *(const short8*)(bbase + (((4 * kk + q8) ^ rx) << 3));

            f32x4 acc[4];
#pragma unroll
            for (int tr = 0; tr < 4; ++tr)
#pragma unroll
                for (int r = 0; r < 4; ++r) acc[tr][r] = 0.0f;

            // MFMA on first half; compiler hoists second-half loads into it
#pragma unroll
            for (int kk = 0; kk < 4; ++kk)
#pragma unroll
                for (int tr = 0; tr < 4; ++tr)
                    acc[tr] = __builtin_amdgcn_mfma_f32_16x16x32_bf16(
                        av[tr][kk], bva[kk], acc[tr], 0, 0, 0);

            short8 bvb[4];
#pragma unroll
            for (int kk = 0; kk < 4; ++kk)
                bvb[kk] = *(const short8*)(bbase + (((4 * (kk + 4) + q8) ^ rx) << 3));

#pragma unroll
            for (int kk = 0; kk < 4; ++kk)
#pragma unroll
                for (int tr = 0; tr < 4; ++tr)
                    acc[tr] = __builtin_amdgcn_mfma_f32_16x16x32_bf16(
                        av[tr][kk + 4], bvb[kk], acc[tr], 0, 0, 0);

            // screen: conservative upper bound on t2 over this lane's 16 elems
            float gmax = acc[0][0];
#pragma unroll
            for (int tr = 0; tr < 4; ++tr)
#pragma unroll
                for (int r = 0; r < 4; ++r) gmax = fmaxf(gmax, acc[tr][r]);
            const float bound = fmaf(gmax, c2, armax + bc);

            if (__any(bound >= -115.0f)) {
                // exact slow path (diagonal-touching tiles, ~1%)
#pragma unroll
                for (int tr = 0; tr < 4; ++tr)
#pragma unroll
                    for (int r = 0; r < 4; ++r) {
                        float g = acc[tr][r];
                        float t2 = fminf(fmaf(g, c2, ar[tr * 4 + r] + bc), 0.0f);
                        float e = __builtin_amdgcn_exp2f(t2);
                        Sr[tr * 4 + r] += e;
                        Mr[tr * 4 + r] = fmaf(e, t2, Mr[tr * 4 + r]);
                    }
            }
            // else: all values underflow fp32 -> contribute exactly 0
        }
    }

    // row-sum commit: reduce across the 16 col-lanes (lane bits 0..3)
#pragma unroll
    for (int m = 1; m <= 8; m <<= 1)
#pragma unroll
        for (int k = 0; k < 16; ++k) {
            Sr[k] += __shfl_xor(Sr[k], m, 64);
            Mr[k] += __shfl_xor(Mr[k], m, 64);
        }
    if (c == 0) {
        const float LN2 = 0.69314718f;   // Mr holds sum e*log2(k); rescale to ln
#pragma unroll
        for (int k = 0; k < 16; ++k) {
            int row = rowbase + wv * 64 + (k >> 2) * 16 + q8 * 4 + (k & 3);
            atomicAdd(&Sarr[row], Sr[k]);
            atomicAdd(&Larr[row], Mr[k] * LN2);
        }
    }
}

// Kernel 2 (merged ctrl+scale): per row H = log(S) - L/S,
// cs = sigmoid(-(H - target)/T); write scaled features + control signal.
__global__ __launch_bounds__(256) void k_finish(const float* __restrict__ x,
                                                const float* __restrict__ Sarr,
                                                const float* __restrict__ Larr,
                                                const float* __restrict__ target,
                                                const float* __restrict__ temp,
                                                float* __restrict__ out) {
    const int gid = blockIdx.x * 256 + threadIdx.x;  // float4 index
    const int row = gid >> 6;                        // 64 float4 per row
    float S = Sarr[row], L = Larr[row];
    float H = __logf(S) - L / S;
    float z = (H - target[0]) / temp[0];
    float cs = 1.0f / (1.0f + __expf(z));
    float4 v = ((const float4*)x)[gid];
    float4 o;
    o.x = v.x * cs; o.y = v.y * cs; o.z = v.z * cs; o.w = v.w * cs;
    ((float4*)out)[gid] = o;
    if ((gid & 63) == 0) out[(size_t)N * D + row] = cs;  // control_signal section
}

extern "C" void kernel_launch(void* const* d_in, const int* in_sizes, int n_in,
                              void* d_out, int out_size, void* d_ws, size_t ws_size,
                              hipStream_t stream) {
    const float* x = (const float*)d_in[0];       // features [4,2048,256]
    const float* target = (const float*)d_in[7];  // target_entropy [1]
    const float* temp = (const float*)d_in[8];    // temperature [1]
    float* out = (float*)d_out;

    float* wsf = (float*)d_ws;
    float* sq = wsf;
    float* Sarr = wsf + N;
    float* Larr = wsf + 2 * N;

    // bf16 copy of X: in ws if it fits, else park it in d_out's first 4 MB
    // (k_finish only writes d_out after k_gram has fully consumed xb)
    const size_t need = 3 * (size_t)N * sizeof(float) + (size_t)N * D * sizeof(unsigned short);
    unsigned short* xb = (ws_size >= need) ? (unsigned short*)(wsf + 3 * N)
                                           : (unsigned short*)d_out;

    k_cvt<<<N / 4, 256, 0, stream>>>(x, xb, sq, Sarr, Larr);
    k_gram<<<dim3(32, 16), 256, 0, stream>>>(xb, sq, temp, Sarr, Larr);
    k_finish<<<(N * (D / 4)) / 256, 256, 0, stream>>>(x, Sarr, Larr, target, temp, out);
}